// Round 1
// baseline (595.510 us; speedup 1.0000x reference)
//
#include <hip/hip_runtime.h>

#define NEGV (-10000.0f)
#define EPSV (1e-5f)

constexpr int Bsz = 4096, Nv = 64, Hd = 128, DEPTH = 3, H2 = 64;

__global__ __launch_bounds__(256, 2)
void subgraph_kernel(const float* __restrict__ hidden, const int* __restrict__ lvn,
                     const float* __restrict__ Ws, const float* __restrict__ bsv,
                     const float* __restrict__ lnw, const float* __restrict__ lnb,
                     float* __restrict__ out)
{
    __shared__ float hs[Nv][Hd + 4];   // 64 x 132 fp32, padded stride
    __shared__ float w[Hd][H2];        // 128 x 64 fp32 (current layer W)

    const int b = blockIdx.x;
    const int t = threadIdx.x;
    const int L = lvn[b];

    // ---- load hidden_states[b] (64x128) into LDS, float4-coalesced ----
    const float4* src = (const float4*)(hidden + (size_t)b * Nv * Hd);
#pragma unroll
    for (int i = 0; i < 8; ++i) {
        int idx4 = t + i * 256;          // 0..2047
        float4 v = src[idx4];
        int flat = idx4 * 4;
        int n = flat >> 7;               // / 128
        int h = flat & 127;
        *(float4*)&hs[n][h] = v;
    }

    const int tx = t & 15, ty = t >> 4;
    const int r0 = ty * 4, c0 = tx * 4;   // this thread's 4x4 output block
    const int kcol = t >> 2, kpart = t & 3; // top2 phase: 4 lanes per column

    __syncthreads();

    for (int l = 0; l < DEPTH; ++l) {
        // ---- stage W[l] (128x64) into LDS ----
        const float4* wsrc = (const float4*)(Ws + (size_t)l * Hd * H2);
#pragma unroll
        for (int i = 0; i < 8; ++i) {
            int idx4 = t + i * 256;
            ((float4*)w)[idx4] = wsrc[idx4];
        }
        __syncthreads();

        // ---- GEMM: x[64][64] = hs[64][128] @ w[128][64]; 4x4 per thread ----
        float acc[4][4] = {};
#pragma unroll
        for (int h = 0; h < Hd; h += 4) {
            float4 a0 = *(const float4*)&hs[r0 + 0][h];
            float4 a1 = *(const float4*)&hs[r0 + 1][h];
            float4 a2 = *(const float4*)&hs[r0 + 2][h];
            float4 a3 = *(const float4*)&hs[r0 + 3][h];
            float4 b0 = *(const float4*)&w[h + 0][c0];
            float4 b1 = *(const float4*)&w[h + 1][c0];
            float4 b2 = *(const float4*)&w[h + 2][c0];
            float4 b3 = *(const float4*)&w[h + 3][c0];
#define ROWF(i, ai) \
            acc[i][0] += ai.x*b0.x + ai.y*b1.x + ai.z*b2.x + ai.w*b3.x; \
            acc[i][1] += ai.x*b0.y + ai.y*b1.y + ai.z*b2.y + ai.w*b3.y; \
            acc[i][2] += ai.x*b0.z + ai.y*b1.z + ai.z*b2.z + ai.w*b3.z; \
            acc[i][3] += ai.x*b0.w + ai.y*b1.w + ai.z*b2.w + ai.w*b3.w;
            ROWF(0, a0) ROWF(1, a1) ROWF(2, a2) ROWF(3, a3)
#undef ROWF
        }

        // ---- bias + LayerNorm(64) + ReLU, row stats via shfl over 16 tx lanes ----
        float4 bias = *(const float4*)(bsv + l * H2 + c0);
        float4 gw   = *(const float4*)(lnw + l * H2 + c0);
        float4 gb   = *(const float4*)(lnb + l * H2 + c0);
        float4 encv[4];
#pragma unroll
        for (int i = 0; i < 4; ++i) {
            float x0 = acc[i][0] + bias.x;
            float x1 = acc[i][1] + bias.y;
            float x2 = acc[i][2] + bias.z;
            float x3 = acc[i][3] + bias.w;
            float s = x0 + x1 + x2 + x3;
            float q = x0*x0 + x1*x1 + x2*x2 + x3*x3;
#pragma unroll
            for (int m = 1; m < 16; m <<= 1) {
                s += __shfl_xor(s, m, 64);
                q += __shfl_xor(q, m, 64);
            }
            float mu  = s * (1.0f / 64.0f);
            float var = q * (1.0f / 64.0f) - mu * mu;
            var = fmaxf(var, 0.0f);
            float rstd = rsqrtf(var + EPSV);
            encv[i].x = fmaxf(0.0f, gw.x * (x0 - mu) * rstd + gb.x);
            encv[i].y = fmaxf(0.0f, gw.y * (x1 - mu) * rstd + gb.y);
            encv[i].z = fmaxf(0.0f, gw.z * (x2 - mu) * rstd + gb.z);
            encv[i].w = fmaxf(0.0f, gw.w * (x3 - mu) * rstd + gb.w);
        }

        // all GEMM reads of old hs are done before we overwrite
        __syncthreads();
#pragma unroll
        for (int i = 0; i < 4; ++i)
            *(float4*)&hs[r0 + i][c0] = encv[i];   // enc -> hs[:, 0:64]
        __syncthreads();

        // ---- column-wise top2 over n (leave-one-out max), 4 lanes per column ----
        float t1 = -3.4e38f, t2 = -3.4e38f;
        float mvals[16];
#pragma unroll
        for (int jj = 0; jj < 16; ++jj) {
            int r = kpart * 16 + jj;
            float mv = hs[r][kcol] + ((r >= L) ? NEGV : 0.0f);
            mvals[jj] = mv;
            if (mv > t1) { t2 = t1; t1 = mv; }
            else if (mv > t2) { t2 = mv; }
        }
#pragma unroll
        for (int m = 1; m < 4; m <<= 1) {
            float o1 = __shfl_xor(t1, m, 64);
            float o2 = __shfl_xor(t2, m, 64);
            float hi = fmaxf(t1, o1);
            float lo = fminf(t1, o1);
            t2 = fmaxf(lo, fmaxf(t2, o2));
            t1 = hi;
        }
#pragma unroll
        for (int jj = 0; jj < 16; ++jj) {
            int r = kpart * 16 + jj;
            float mv = mvals[jj];
            float loo = (mv == t1) ? t2 : t1;   // exact-equality select, matches jnp
            loo = fmaxf(loo, mv + NEGV);
            loo = fmaxf(loo, 0.0f);
            hs[r][H2 + kcol] = loo;             // loo -> hs[:, 64:128]
        }
        __syncthreads();
    }

    // ---- out[b][h] = max over n of hs[n][h] ----
    if (t < Hd) {
        float v = -3.4e38f;
#pragma unroll
        for (int n = 0; n < Nv; ++n) v = fmaxf(v, hs[n][t]);
        out[(size_t)b * Hd + t] = v;
    }
}

extern "C" void kernel_launch(void* const* d_in, const int* in_sizes, int n_in,
                              void* d_out, int out_size, void* d_ws, size_t ws_size,
                              hipStream_t stream) {
    const float* hidden = (const float*)d_in[0];
    const int*   lvn    = (const int*)d_in[1];
    const float* Ws     = (const float*)d_in[2];
    const float* bs     = (const float*)d_in[3];
    const float* lnwp   = (const float*)d_in[4];
    const float* lnbp   = (const float*)d_in[5];
    float* outp = (float*)d_out;
    subgraph_kernel<<<Bsz, 256, 0, stream>>>(hidden, lvn, Ws, bs, lnwp, lnbp, outp);
}

// Round 2
// 82.911 us; speedup vs baseline: 7.1825x; 7.1825x over previous
//
#include <hip/hip_runtime.h>

#define NEGV (-10000.0f)
#define EPSV (1e-5f)

typedef __attribute__((ext_vector_type(8))) short short8;
typedef __attribute__((ext_vector_type(4))) float floatx4;

constexpr int Bsz = 4096, Nv = 64, Hd = 128, DEPTH = 3, H2 = 64;

__device__ __forceinline__ unsigned short f2b(float f) {
    unsigned int u = __builtin_bit_cast(unsigned int, f);
    u += 0x7fffu + ((u >> 16) & 1u);          // RNE to bf16
    return (unsigned short)(u >> 16);
}

// Pack W[l] (128x64 f32, row-major over k) into bf16 fragment order:
// wt[l][kt][hi][col][j] = bf16(W[l][kt*32+hi*8+j][col]); 16KB per layer.
__global__ void prep_w(const float* __restrict__ Ws, unsigned short* __restrict__ wt) {
    int idx = blockIdx.x * 256 + threadIdx.x;
    if (idx < DEPTH * 8192) {
        int l = idx >> 13, o = idx & 8191;
        int j = o & 7, col = (o >> 3) & 63, hi = (o >> 9) & 3, kt = o >> 11;
        int k = kt * 32 + hi * 8 + j;
        wt[idx] = f2b(Ws[l * 8192 + k * 64 + col]);
    }
}

__global__ __launch_bounds__(256, 3)
void subgraph_kernel(const float* __restrict__ hidden, const int* __restrict__ lvn,
                     const unsigned short* __restrict__ wt,
                     const float* __restrict__ bsv, const float* __restrict__ lnw,
                     const float* __restrict__ lnb, float* __restrict__ out)
{
    __shared__ float hs[Nv][132];          // 64 x 132 f32 (33792 B), rows 16B-aligned
    __shared__ unsigned short wl[8192];    // W[l] bf16 fragment-order (16384 B)

    const int b = blockIdx.x, t = threadIdx.x;
    const int L = lvn[b];
    const int lane = t & 63, wid = t >> 6;     // 4 waves
    const int lr = lane & 15, hi = lane >> 4;  // MFMA lane decomposition
    const int arow = wid * 16 + lr;            // this wave's A-row for lane

    // ---- stage hidden_states[b] (64x128 f32) into LDS ----
    const float4* src = (const float4*)(hidden + (size_t)b * Nv * Hd);
#pragma unroll
    for (int i = 0; i < 8; ++i) {
        int idx4 = t + i * 256;
        float4 v = src[idx4];
        int flat = idx4 * 4, n = flat >> 7, h = flat & 127;
        *(float4*)&hs[n][h] = v;
    }

    const int kcol = t >> 2, kpart = t & 3;    // top2 phase: 4 lanes per column

    for (int l = 0; l < DEPTH; ++l) {
        // ---- stage Wt[l] (bf16, fragment order) from workspace ----
        const int4* wsrc = (const int4*)(wt + l * 8192);
#pragma unroll
        for (int i = 0; i < 4; ++i)
            ((int4*)wl)[t + i * 256] = wsrc[t + i * 256];
        __syncthreads();                       // (a) W + (l==0) hidden visible

        // ---- A fragments: own strip row, f32 -> bf16 on the fly ----
        short8 af[4];
#pragma unroll
        for (int kt = 0; kt < 4; ++kt) {
            float4 f0 = *(const float4*)&hs[arow][kt * 32 + hi * 8];
            float4 f1 = *(const float4*)&hs[arow][kt * 32 + hi * 8 + 4];
            short8 a;
            a[0] = (short)f2b(f0.x); a[1] = (short)f2b(f0.y);
            a[2] = (short)f2b(f0.z); a[3] = (short)f2b(f0.w);
            a[4] = (short)f2b(f1.x); a[5] = (short)f2b(f1.y);
            a[6] = (short)f2b(f1.z); a[7] = (short)f2b(f1.w);
            af[kt] = a;
        }

        // ---- MFMA: 4 column tiles x 4 k tiles ----
        floatx4 acc[4];
#pragma unroll
        for (int ct = 0; ct < 4; ++ct) { floatx4 z = {0.f, 0.f, 0.f, 0.f}; acc[ct] = z; }
#pragma unroll
        for (int ct = 0; ct < 4; ++ct)
#pragma unroll
            for (int kt = 0; kt < 4; ++kt) {
                short8 bf = *(const short8*)(wl + ((kt * 4 + hi) * 64 + ct * 16 + lr) * 8);
                acc[ct] = __builtin_amdgcn_mfma_f32_16x16x32_bf16(af[kt], bf, acc[ct], 0, 0, 0);
            }

        // ---- bias + LayerNorm(64 cols) + ReLU; C/D: col=ct*16+lr, row=wid*16+hi*4+reg
        float bc[4], gwv[4], gbv[4];
#pragma unroll
        for (int ct = 0; ct < 4; ++ct) {
            bc[ct]  = bsv[l * H2 + ct * 16 + lr];
            gwv[ct] = lnw[l * H2 + ct * 16 + lr];
            gbv[ct] = lnb[l * H2 + ct * 16 + lr];
        }
#pragma unroll
        for (int reg = 0; reg < 4; ++reg) {
            float x0 = acc[0][reg] + bc[0];
            float x1 = acc[1][reg] + bc[1];
            float x2 = acc[2][reg] + bc[2];
            float x3 = acc[3][reg] + bc[3];
            float s = x0 + x1 + x2 + x3;
            float q = x0 * x0 + x1 * x1 + x2 * x2 + x3 * x3;
#pragma unroll
            for (int m = 1; m < 16; m <<= 1) {
                s += __shfl_xor(s, m, 64);
                q += __shfl_xor(q, m, 64);
            }
            float mu  = s * (1.0f / 64.0f);
            float var = q * (1.0f / 64.0f) - mu * mu;
            var = fmaxf(var, 0.0f);
            float rstd = rsqrtf(var + EPSV);
            int row = wid * 16 + hi * 4 + reg;   // wave-local row: no barrier needed
            hs[row][0  + lr] = fmaxf(gwv[0] * (x0 - mu) * rstd + gbv[0], 0.0f);
            hs[row][16 + lr] = fmaxf(gwv[1] * (x1 - mu) * rstd + gbv[1], 0.0f);
            hs[row][32 + lr] = fmaxf(gwv[2] * (x2 - mu) * rstd + gbv[2], 0.0f);
            hs[row][48 + lr] = fmaxf(gwv[3] * (x3 - mu) * rstd + gbv[3], 0.0f);
        }
        __syncthreads();                       // (b) enc visible to all

        // ---- column top2 -> leave-one-out max; rows r = jj*4 + kpart ----
        float t1 = -3.4e38f, t2 = -3.4e38f;
        float mvals[16];
#pragma unroll
        for (int jj = 0; jj < 16; ++jj) {
            int r = jj * 4 + kpart;
            float mv = hs[r][kcol] + ((r >= L) ? NEGV : 0.0f);
            mvals[jj] = mv;
            if (mv > t1) { t2 = t1; t1 = mv; }
            else if (mv > t2) { t2 = mv; }
        }
#pragma unroll
        for (int m = 1; m < 4; m <<= 1) {
            float o1 = __shfl_xor(t1, m, 64);
            float o2 = __shfl_xor(t2, m, 64);
            float hi1 = fmaxf(t1, o1);
            float lo1 = fminf(t1, o1);
            t2 = fmaxf(lo1, fmaxf(t2, o2));
            t1 = hi1;
        }
#pragma unroll
        for (int jj = 0; jj < 16; ++jj) {
            int r = jj * 4 + kpart;
            float mv = mvals[jj];
            float loo = (mv == t1) ? t2 : t1;  // exact-equality select, matches jnp
            loo = fmaxf(loo, mv + NEGV);
            loo = fmaxf(loo, 0.0f);
            hs[r][H2 + kcol] = loo;
        }
        __syncthreads();                       // (c) loo visible; wl safe to overwrite
    }

    // ---- out[b][h] = max over n of hs[n][h] ----
    if (t < Hd) {
        float v = -3.4e38f;
#pragma unroll
        for (int n = 0; n < Nv; ++n) v = fmaxf(v, hs[n][t]);
        out[(size_t)b * Hd + t] = v;
    }
}

extern "C" void kernel_launch(void* const* d_in, const int* in_sizes, int n_in,
                              void* d_out, int out_size, void* d_ws, size_t ws_size,
                              hipStream_t stream) {
    const float* hidden = (const float*)d_in[0];
    const int*   lvn    = (const int*)d_in[1];
    const float* Ws     = (const float*)d_in[2];
    const float* bs     = (const float*)d_in[3];
    const float* lnwp   = (const float*)d_in[4];
    const float* lnbp   = (const float*)d_in[5];
    unsigned short* wt  = (unsigned short*)d_ws;   // 48 KB bf16 fragment-packed W
    float* outp = (float*)d_out;

    prep_w<<<(DEPTH * 8192 + 255) / 256, 256, 0, stream>>>(Ws, wt);
    subgraph_kernel<<<Bsz, 256, 0, stream>>>(hidden, lvn, wt, bs, lnwp, lnbp, outp);
}

// Round 3
// 68.975 us; speedup vs baseline: 8.6337x; 1.2020x over previous
//
#include <hip/hip_runtime.h>
#include <hip/hip_bf16.h>

#define NEGV (-10000.0f)
#define EPSV (1e-5f)
#define NINF (-3.4e38f)

typedef __attribute__((ext_vector_type(8))) short short8;
typedef __attribute__((ext_vector_type(4))) float floatx4;

constexpr int Bsz = 4096, Nv = 64, Hd = 128, DEPTH = 3, H2 = 64;
constexpr int HSTR = 136;   // hs row stride in bf16 elems: 272 B = 17x16 (b128-aligned), 68 dwords = 4 mod 32

struct alignas(8) BH4 { __hip_bfloat162 a, b; };

__device__ __forceinline__ unsigned short f2b(float f) {
    unsigned int u = __builtin_bit_cast(unsigned int, f);
    u += 0x7fffu + ((u >> 16) & 1u);          // RNE to bf16
    return (unsigned short)(u >> 16);
}

// top-2 helpers (duplicate-preserving, matches jax top_k semantics)
__device__ __forceinline__ void t2ins(float& t1, float& t2, float v) {
    float lo = fminf(t1, v); t1 = fmaxf(t1, v); t2 = fmaxf(t2, lo);
}
__device__ __forceinline__ void t2merge(float& t1, float& t2, float o1, float o2) {
    float lo = fminf(t1, o1); t1 = fmaxf(t1, o1); t2 = fmaxf(fmaxf(t2, o2), lo);
}

// Pack W[l] (128x64 f32) into bf16 MFMA-fragment order WITH column permutation:
// fragment position (ct,lr) sources actual column 4*lr+ct, so D-lane lr owns
// 4 consecutive output columns across its 4 accumulators.
// wt[((kt*4+hi)*64 + ct*16+lr)*8 + j] = bf16(W[kt*32+hi*8+j][4*lr+ct])
__global__ void prep_w(const float* __restrict__ Ws, unsigned short* __restrict__ wt) {
    int idx = blockIdx.x * 256 + threadIdx.x;
    if (idx < DEPTH * 8192) {
        int l = idx >> 13, o = idx & 8191;
        int j = o & 7, q = (o >> 3) & 63, hi = (o >> 9) & 3, kt = o >> 11;
        int k = kt * 32 + hi * 8 + j;
        int srccol = (q & 15) * 4 + (q >> 4);
        wt[idx] = f2b(Ws[l * 8192 + k * 64 + srccol]);
    }
}

__global__ __launch_bounds__(256, 4)
void subgraph_kernel(const float* __restrict__ hidden, const int* __restrict__ lvn,
                     const unsigned short* __restrict__ wt,
                     const float* __restrict__ bsv, const float* __restrict__ lnw,
                     const float* __restrict__ lnb, float* __restrict__ out)
{
    __shared__ __hip_bfloat16 hsb[Nv][HSTR];   // 64 x 136 bf16 = 17408 B
    __shared__ float scbuf[4][128];            // 2048 B: top2 pairs / final maxes

    const int b = blockIdx.x, t = threadIdx.x;
    const int L = lvn[b];
    const int lane = t & 63, wid = t >> 6;     // 4 waves
    const int lr = lane & 15, hi = lane >> 4;
    const int arow = wid * 16 + lr;            // wave's A-row for this lane

    // ---- stage hidden_states[b] (64x128 f32) -> bf16 LDS ----
    const float4* src = (const float4*)(hidden + (size_t)b * Nv * Hd);
#pragma unroll
    for (int i = 0; i < 8; ++i) {
        int idx4 = t + i * 256;
        float4 v = src[idx4];
        int flat = idx4 * 4, n = flat >> 7, h = flat & 127;
        BH4 pk;
        pk.a = __float22bfloat162_rn(make_float2(v.x, v.y));
        pk.b = __float22bfloat162_rn(make_float2(v.z, v.w));
        *(BH4*)&hsb[n][h] = pk;
    }

    float madd[4];                              // pad mask addend per reg's row
#pragma unroll
    for (int reg = 0; reg < 4; ++reg) {
        int row = wid * 16 + hi * 4 + reg;
        madd[reg] = (row >= L) ? NEGV : 0.0f;
    }
    __syncthreads();

    float encmax[4], loomax[4];                 // set at l==2

    for (int l = 0; l < DEPTH; ++l) {
        const unsigned short* wbase = wt + l * 8192;

        // ---- A fragments: 4 x ds_read_b128 (bf16, b128-aligned, 2-way free) ----
        short8 af[4];
#pragma unroll
        for (int kt = 0; kt < 4; ++kt)
            af[kt] = *(const short8*)&hsb[arow][kt * 32 + hi * 8];

        // ---- MFMA: B frags straight from global (L1-resident) ----
        floatx4 acc[4];
#pragma unroll
        for (int ct = 0; ct < 4; ++ct) { floatx4 z = {0.f, 0.f, 0.f, 0.f}; acc[ct] = z; }
#pragma unroll
        for (int kt = 0; kt < 4; ++kt)
#pragma unroll
            for (int ct = 0; ct < 4; ++ct) {
                short8 bf = *(const short8*)(wbase + ((kt * 4 + hi) * 64 + ct * 16 + lr) * 8);
                acc[ct] = __builtin_amdgcn_mfma_f32_16x16x32_bf16(af[kt], bf, acc[ct], 0, 0, 0);
            }

        // ---- bias + LayerNorm + ReLU; lane owns actual cols 4*lr..4*lr+3 ----
        float4 bias = *(const float4*)(bsv + l * H2 + 4 * lr);
        float4 gw   = *(const float4*)(lnw + l * H2 + 4 * lr);
        float4 gb   = *(const float4*)(lnb + l * H2 + 4 * lr);
        float enc[4][4];                        // [ct][reg]
#pragma unroll
        for (int reg = 0; reg < 4; ++reg) {
            float x0 = acc[0][reg] + bias.x;
            float x1 = acc[1][reg] + bias.y;
            float x2 = acc[2][reg] + bias.z;
            float x3 = acc[3][reg] + bias.w;
            float s = x0 + x1 + x2 + x3;
            float q = x0 * x0 + x1 * x1 + x2 * x2 + x3 * x3;
#pragma unroll
            for (int m = 1; m < 16; m <<= 1) {
                s += __shfl_xor(s, m, 64);
                q += __shfl_xor(q, m, 64);
            }
            float mu  = s * (1.0f / 64.0f);
            float var = fmaxf(q * (1.0f / 64.0f) - mu * mu, 0.0f);
            float rstd = rsqrtf(var + EPSV);
            enc[0][reg] = fmaxf(gw.x * (x0 - mu) * rstd + gb.x, 0.0f);
            enc[1][reg] = fmaxf(gw.y * (x1 - mu) * rstd + gb.y, 0.0f);
            enc[2][reg] = fmaxf(gw.z * (x2 - mu) * rstd + gb.z, 0.0f);
            enc[3][reg] = fmaxf(gw.w * (x3 - mu) * rstd + gb.w, 0.0f);
        }

        // ---- in-register masked top2: 4 regs in-lane, then hi-groups via shfl ----
        float t1[4], t2[4];
#pragma unroll
        for (int ct = 0; ct < 4; ++ct) {
            float a0 = enc[ct][0] + madd[0], a1 = enc[ct][1] + madd[1];
            float a2 = enc[ct][2] + madd[2], a3 = enc[ct][3] + madd[3];
            t1[ct] = fmaxf(a0, a1); t2[ct] = fminf(a0, a1);
            t2ins(t1[ct], t2[ct], a2);
            t2ins(t1[ct], t2[ct], a3);
            t2merge(t1[ct], t2[ct], __shfl_xor(t1[ct], 16, 64), __shfl_xor(t2[ct], 16, 64));
            t2merge(t1[ct], t2[ct], __shfl_xor(t1[ct], 32, 64), __shfl_xor(t2[ct], 32, 64));
        }
        if (hi == 0) {                          // wave-level top2 -> LDS (conflict-free)
#pragma unroll
            for (int ct = 0; ct < 4; ++ct)
                ((float2*)scbuf[wid])[ct * 16 + lr] = make_float2(t1[ct], t2[ct]);
        }
        __syncthreads();

        // ---- redundant cross-wave merge (broadcast reads, no extra barrier) ----
        float f1[4], f2[4];
#pragma unroll
        for (int ct = 0; ct < 4; ++ct) { f1[ct] = NINF; f2[ct] = NINF; }
#pragma unroll
        for (int w = 0; w < 4; ++w)
#pragma unroll
            for (int ct = 0; ct < 4; ++ct) {
                float2 p = ((const float2*)scbuf[w])[ct * 16 + lr];
                t2merge(f1[ct], f2[ct], p.x, p.y);
            }

        if (l < DEPTH - 1) {
            // ---- loo + write enc/loo to hs (bf16, 8B vector writes, conflict-free) ----
#pragma unroll
            for (int reg = 0; reg < 4; ++reg) {
                int row = wid * 16 + hi * 4 + reg;
                float lo[4];
#pragma unroll
                for (int ct = 0; ct < 4; ++ct) {
                    float mv = enc[ct][reg] + madd[reg];
                    float v = (mv == f1[ct]) ? f2[ct] : f1[ct];   // exact-eq select
                    v = fmaxf(v, mv + NEGV);
                    lo[ct] = fmaxf(v, 0.0f);
                }
                BH4 we, wl_;
                we.a  = __float22bfloat162_rn(make_float2(enc[0][reg], enc[1][reg]));
                we.b  = __float22bfloat162_rn(make_float2(enc[2][reg], enc[3][reg]));
                wl_.a = __float22bfloat162_rn(make_float2(lo[0], lo[1]));
                wl_.b = __float22bfloat162_rn(make_float2(lo[2], lo[3]));
                *(BH4*)&hsb[row][4 * lr]      = we;
                *(BH4*)&hsb[row][64 + 4 * lr] = wl_;
            }
            __syncthreads();
        } else {
            // ---- final layer: reduce enc/loo maxes fully in-register ----
#pragma unroll
            for (int ct = 0; ct < 4; ++ct) {
                float em = fmaxf(fmaxf(enc[ct][0], enc[ct][1]), fmaxf(enc[ct][2], enc[ct][3]));
                float lm = NINF;
#pragma unroll
                for (int reg = 0; reg < 4; ++reg) {
                    float mv = enc[ct][reg] + madd[reg];
                    float v = (mv == f1[ct]) ? f2[ct] : f1[ct];
                    v = fmaxf(v, mv + NEGV);
                    lm = fmaxf(lm, fmaxf(v, 0.0f));
                }
                em = fmaxf(em, __shfl_xor(em, 16, 64));
                em = fmaxf(em, __shfl_xor(em, 32, 64));
                lm = fmaxf(lm, __shfl_xor(lm, 16, 64));
                lm = fmaxf(lm, __shfl_xor(lm, 32, 64));
                encmax[ct] = em; loomax[ct] = lm;
            }
        }
    }

    // ---- cross-wave final max + output ----
    __syncthreads();                            // scbuf reuse
    if (hi == 0) {
        float4 e = make_float4(encmax[0], encmax[1], encmax[2], encmax[3]);
        float4 o = make_float4(loomax[0], loomax[1], loomax[2], loomax[3]);
        *(float4*)&scbuf[wid][4 * lr]      = e;
        *(float4*)&scbuf[wid][64 + 4 * lr] = o;
    }
    __syncthreads();
    if (t < Hd) {
        float v = fmaxf(fmaxf(scbuf[0][t], scbuf[1][t]), fmaxf(scbuf[2][t], scbuf[3][t]));
        out[(size_t)b * Hd + t] = v;
    }
}

extern "C" void kernel_launch(void* const* d_in, const int* in_sizes, int n_in,
                              void* d_out, int out_size, void* d_ws, size_t ws_size,
                              hipStream_t stream) {
    const float* hidden = (const float*)d_in[0];
    const int*   lvn    = (const int*)d_in[1];
    const float* Ws     = (const float*)d_in[2];
    const float* bs     = (const float*)d_in[3];
    const float* lnwp   = (const float*)d_in[4];
    const float* lnbp   = (const float*)d_in[5];
    unsigned short* wt  = (unsigned short*)d_ws;   // 48 KB bf16 fragment-packed W
    float* outp = (float*)d_out;

    prep_w<<<(DEPTH * 8192 + 255) / 256, 256, 0, stream>>>(Ws, wt);
    subgraph_kernel<<<Bsz, 256, 0, stream>>>(hidden, lvn, wt, bs, lnwp, lnbp, outp);
}

// Round 4
// 68.261 us; speedup vs baseline: 8.7241x; 1.0105x over previous
//
#include <hip/hip_runtime.h>
#include <hip/hip_bf16.h>

#define NEGV (-10000.0f)
#define EPSV (1e-5f)
#define NINF (-3.4e38f)

typedef __attribute__((ext_vector_type(8))) short short8;
typedef __attribute__((ext_vector_type(4))) float floatx4;

constexpr int Bsz = 4096, Nv = 64, Hd = 128, DEPTH = 3, H2 = 64;
constexpr int HSTR = 136;   // bf16 row stride: 272 B = 17x16B (b128-aligned, 2-way-free banks)

struct alignas(8) BH4 { __hip_bfloat162 a, b; };

__device__ __forceinline__ unsigned short f2b(float f) {
    unsigned int u = __builtin_bit_cast(unsigned int, f);
    u += 0x7fffu + ((u >> 16) & 1u);          // RNE to bf16
    return (unsigned short)(u >> 16);
}

// top-2 helpers (duplicate-preserving, matches jax top_k semantics)
__device__ __forceinline__ void t2ins(float& t1, float& t2, float v) {
    float lo = fminf(t1, v); t1 = fmaxf(t1, v); t2 = fmaxf(t2, lo);
}
__device__ __forceinline__ void t2merge(float& t1, float& t2, float o1, float o2) {
    float lo = fminf(t1, o1); t1 = fmaxf(t1, o1); t2 = fmaxf(fmaxf(t2, o2), lo);
}

// Pack W[l] (128x64 f32) into bf16 MFMA-fragment order WITH column permutation:
// fragment position (ct,lr) sources actual column 4*lr+ct, so D-lane lr owns
// 4 consecutive output columns across its 4 accumulators.
// wt[((kt*4+hi)*64 + ct*16+lr)*8 + j] = bf16(W[kt*32+hi*8+j][4*lr+ct])
__global__ void prep_w(const float* __restrict__ Ws, unsigned short* __restrict__ wt) {
    int idx = blockIdx.x * 256 + threadIdx.x;
    if (idx < DEPTH * 8192) {
        int l = idx >> 13, o = idx & 8191;
        int j = o & 7, q = (o >> 3) & 63, hi = (o >> 9) & 3, kt = o >> 11;
        int k = kt * 32 + hi * 8 + j;
        int srccol = (q & 15) * 4 + (q >> 4);
        wt[idx] = f2b(Ws[l * 8192 + k * 64 + srccol]);
    }
}

__global__ __launch_bounds__(256, 2)
void subgraph_kernel(const float* __restrict__ hidden, const int* __restrict__ lvn,
                     const unsigned short* __restrict__ wt,
                     const float* __restrict__ bsv, const float* __restrict__ lnw,
                     const float* __restrict__ lnb, float* __restrict__ out)
{
    // wave-private enc/loo buffer; no __syncthreads anywhere in this kernel
    __shared__ __hip_bfloat16 hsw[4][Nv][HSTR];   // 4 x 17408 B = 69632 B

    const int t = threadIdx.x;
    const int lane = t & 63, wid = t >> 6;
    const int b = blockIdx.x * 4 + wid;           // one polyline per wave
    const int lr = lane & 15, hi = lane >> 4;
    const int L = lvn[b];

    __hip_bfloat16 (*hs)[HSTR] = hsw[wid];

    // pad-mask addend per (rt,reg): row = rt*16 + hi*4 + reg
    float madd[4][4];
#pragma unroll
    for (int rt = 0; rt < 4; ++rt)
#pragma unroll
        for (int reg = 0; reg < 4; ++reg)
            madd[rt][reg] = ((rt * 16 + hi * 4 + reg) >= L) ? NEGV : 0.0f;

    const float4* ab = (const float4*)(hidden + (size_t)b * Nv * Hd);
    float encmax[4], loomax[4];

#pragma unroll
    for (int l = 0; l < DEPTH; ++l) {
        const short8* wfrag = (const short8*)(wt + l * 8192);

        // ---- GEMM: acc[rt][ct] over 4 k-tiles; A from global (l==0) or LDS ----
        floatx4 acc[4][4];
#pragma unroll
        for (int rt = 0; rt < 4; ++rt)
#pragma unroll
            for (int ct = 0; ct < 4; ++ct) { floatx4 z = {0.f,0.f,0.f,0.f}; acc[rt][ct] = z; }

#pragma unroll
        for (int kt = 0; kt < 4; ++kt) {
            short8 af[4];
            if (l == 0) {
#pragma unroll
                for (int rt = 0; rt < 4; ++rt) {
                    int fi = (rt * 16 + lr) * 32 + kt * 8 + hi * 2;
                    float4 f0 = ab[fi], f1 = ab[fi + 1];
                    union { short8 s; __hip_bfloat162 h[4]; } u;
                    u.h[0] = __float22bfloat162_rn(make_float2(f0.x, f0.y));
                    u.h[1] = __float22bfloat162_rn(make_float2(f0.z, f0.w));
                    u.h[2] = __float22bfloat162_rn(make_float2(f1.x, f1.y));
                    u.h[3] = __float22bfloat162_rn(make_float2(f1.z, f1.w));
                    af[rt] = u.s;
                }
            } else {
#pragma unroll
                for (int rt = 0; rt < 4; ++rt)
                    af[rt] = *(const short8*)&hs[rt * 16 + lr][kt * 32 + hi * 8];
            }
#pragma unroll
            for (int ct = 0; ct < 4; ++ct) {
                short8 bf = wfrag[(kt * 4 + hi) * 64 + ct * 16 + lr];
#pragma unroll
                for (int rt = 0; rt < 4; ++rt)
                    acc[rt][ct] = __builtin_amdgcn_mfma_f32_16x16x32_bf16(af[rt], bf, acc[rt][ct], 0, 0, 0);
            }
        }

        // ---- bias + LayerNorm + ReLU (in place into acc); lane owns cols 4lr..4lr+3
        float4 bias = *(const float4*)(bsv + l * H2 + 4 * lr);
        float4 gw   = *(const float4*)(lnw + l * H2 + 4 * lr);
        float4 gb   = *(const float4*)(lnb + l * H2 + 4 * lr);
#pragma unroll
        for (int rt = 0; rt < 4; ++rt)
#pragma unroll
            for (int reg = 0; reg < 4; ++reg) {
                float x0 = acc[rt][0][reg] + bias.x;
                float x1 = acc[rt][1][reg] + bias.y;
                float x2 = acc[rt][2][reg] + bias.z;
                float x3 = acc[rt][3][reg] + bias.w;
                float s = x0 + x1 + x2 + x3;
                float q = x0 * x0 + x1 * x1 + x2 * x2 + x3 * x3;
#pragma unroll
                for (int m = 1; m < 16; m <<= 1) {
                    s += __shfl_xor(s, m, 64);
                    q += __shfl_xor(q, m, 64);
                }
                float mu  = s * (1.0f / 64.0f);
                float var = fmaxf(q * (1.0f / 64.0f) - mu * mu, 0.0f);
                float rstd = rsqrtf(var + EPSV);
                acc[rt][0][reg] = fmaxf(gw.x * (x0 - mu) * rstd + gb.x, 0.0f);
                acc[rt][1][reg] = fmaxf(gw.y * (x1 - mu) * rstd + gb.y, 0.0f);
                acc[rt][2][reg] = fmaxf(gw.z * (x2 - mu) * rstd + gb.z, 0.0f);
                acc[rt][3][reg] = fmaxf(gw.w * (x3 - mu) * rstd + gb.w, 0.0f);
            }

        // ---- full-column top2: in-lane over 16 rows, then hi-group merges ----
        float f1v[4], f2v[4];
#pragma unroll
        for (int ct = 0; ct < 4; ++ct) {
            float t1 = NINF, t2 = NINF;
#pragma unroll
            for (int rt = 0; rt < 4; ++rt)
#pragma unroll
                for (int reg = 0; reg < 4; ++reg)
                    t2ins(t1, t2, acc[rt][ct][reg] + madd[rt][reg]);
            t2merge(t1, t2, __shfl_xor(t1, 16, 64), __shfl_xor(t2, 16, 64));
            t2merge(t1, t2, __shfl_xor(t1, 32, 64), __shfl_xor(t2, 32, 64));
            f1v[ct] = t1; f2v[ct] = t2;
        }

        if (l < DEPTH - 1) {
            // ---- loo + write enc/loo as bf16 (8B writes, conflict-free) ----
#pragma unroll
            for (int rt = 0; rt < 4; ++rt)
#pragma unroll
                for (int reg = 0; reg < 4; ++reg) {
                    int row = rt * 16 + hi * 4 + reg;
                    float lo[4];
#pragma unroll
                    for (int ct = 0; ct < 4; ++ct) {
                        float mv = acc[rt][ct][reg] + madd[rt][reg];
                        float v = (mv == f1v[ct]) ? f2v[ct] : f1v[ct];  // exact-eq select
                        v = fmaxf(v, mv + NEGV);
                        lo[ct] = fmaxf(v, 0.0f);
                    }
                    BH4 we, wl_;
                    we.a  = __float22bfloat162_rn(make_float2(acc[rt][0][reg], acc[rt][1][reg]));
                    we.b  = __float22bfloat162_rn(make_float2(acc[rt][2][reg], acc[rt][3][reg]));
                    wl_.a = __float22bfloat162_rn(make_float2(lo[0], lo[1]));
                    wl_.b = __float22bfloat162_rn(make_float2(lo[2], lo[3]));
                    *(BH4*)&hs[row][4 * lr]      = we;
                    *(BH4*)&hs[row][64 + 4 * lr] = wl_;
                }
        } else {
            // ---- final layer: reduce enc/loo maxes fully in-register ----
#pragma unroll
            for (int ct = 0; ct < 4; ++ct) {
                float em = NINF, lm = NINF;
#pragma unroll
                for (int rt = 0; rt < 4; ++rt)
#pragma unroll
                    for (int reg = 0; reg < 4; ++reg) {
                        float e = acc[rt][ct][reg];
                        em = fmaxf(em, e);
                        float mv = e + madd[rt][reg];
                        float v = (mv == f1v[ct]) ? f2v[ct] : f1v[ct];
                        v = fmaxf(v, mv + NEGV);
                        lm = fmaxf(lm, fmaxf(v, 0.0f));
                    }
                em = fmaxf(em, __shfl_xor(em, 16, 64));
                em = fmaxf(em, __shfl_xor(em, 32, 64));
                lm = fmaxf(lm, __shfl_xor(lm, 16, 64));
                lm = fmaxf(lm, __shfl_xor(lm, 32, 64));
                encmax[ct] = em; loomax[ct] = lm;
            }
        }
    }

    // ---- output: lane lr owns cols 4lr..4lr+3 (enc) and 64+4lr.. (loo) ----
    if (hi == 0) {
        float4 e = make_float4(encmax[0], encmax[1], encmax[2], encmax[3]);
        float4 o = make_float4(loomax[0], loomax[1], loomax[2], loomax[3]);
        *(float4*)(out + (size_t)b * Hd + 4 * lr)      = e;
        *(float4*)(out + (size_t)b * Hd + 64 + 4 * lr) = o;
    }
}

extern "C" void kernel_launch(void* const* d_in, const int* in_sizes, int n_in,
                              void* d_out, int out_size, void* d_ws, size_t ws_size,
                              hipStream_t stream) {
    const float* hidden = (const float*)d_in[0];
    const int*   lvn    = (const int*)d_in[1];
    const float* Ws     = (const float*)d_in[2];
    const float* bs     = (const float*)d_in[3];
    const float* lnwp   = (const float*)d_in[4];
    const float* lnbp   = (const float*)d_in[5];
    unsigned short* wt  = (unsigned short*)d_ws;   // 48 KB bf16 fragment-packed W
    float* outp = (float*)d_out;

    prep_w<<<(DEPTH * 8192 + 255) / 256, 256, 0, stream>>>(Ws, wt);
    subgraph_kernel<<<Bsz / 4, 256, 0, stream>>>(hidden, lvn, wt, bs, lnwp, lnbp, outp);
}